// Round 7
// baseline (297.757 us; speedup 1.0000x reference)
//
#include <hip/hip_runtime.h>
#include <hip/hip_bf16.h>
#include <math.h>

#define CH 64
#define TILE 16
#define TROW 72   // LDS A-tile row stride in bf16 elems: 144 B = 9*16 B aligned
#define NXCD 8

typedef short short8 __attribute__((ext_vector_type(8)));
typedef float floatx4 __attribute__((ext_vector_type(4)));

__device__ __forceinline__ float bf2f(unsigned short u) {
    return __uint_as_float(((unsigned int)u) << 16);
}
__device__ __forceinline__ unsigned short f2bf(float f) {
    unsigned int x = __float_as_uint(f);
    unsigned int r = (x + 0x7fff + ((x >> 16) & 1)) >> 16;   // RNE
    return (unsigned short)r;
}

// ---------------------------------------------------------------------------
// XCD-owned histogram: blocks with (blockIdx&7)==g scan ALL edges, count only
// dsts in range g -> all deg-line writes/atomics stay on one XCD's L2.
// blockIdx&7 ~ XCD id is a perf heuristic only; atomics are device-scope, so
// any block->XCD mapping is still correct. Block 0 also runs dtype detection.
// ---------------------------------------------------------------------------
__global__ __launch_bounds__(256) void k_hist(
    const unsigned short* __restrict__ x,
    const int* __restrict__ srcs, const int* __restrict__ dsts,
    int* __restrict__ deg, int* __restrict__ flag,
    int n_edges, int n_nodes)
{
    if (blockIdx.x == 0 && threadIdx.x < 64) {
        unsigned short u = x[2 * threadIdx.x];
        int ex = (u >> 7) & 0xFF;
        bool insane = (ex < 0x60) || (ex > 0x9F);
        unsigned long long m = __ballot(insane);
        if (threadIdx.x == 0) flag[0] = (__popcll(m) > 16) ? 0 : 1;
    }
    const int grp = blockIdx.x & (NXCD - 1);
    const int gidx = blockIdx.x >> 3;
    const int gstride = (gridDim.x >> 3) * 256;
    const int range = (n_nodes + NXCD - 1) / NXCD;
    const int lo = grp * range;
    const int hi = min(n_nodes, lo + range);
    for (int e = gidx * 256 + threadIdx.x; e < n_edges; e += gstride) {
        int d = dsts[e];
        if (d >= lo && d < hi) {
            int s = srcs[e];
            if ((unsigned)s < (unsigned)n_nodes) atomicAdd(&deg[d], 1);
        }
    }
}

// ---------------------------------------------------------------------------
// Exclusive scan: per-1024 block partials -> block-sum scan -> add-back.
// rowptr has n+1 entries; k_scan2 writes rowptr[n] = total.
// ---------------------------------------------------------------------------
__global__ __launch_bounds__(256) void k_scan1(
    const int* __restrict__ deg, int* __restrict__ rowptr,
    int* __restrict__ bsum, int n)
{
    __shared__ int ts[256];
    int t = threadIdx.x;
    int base = blockIdx.x * 1024 + t * 4;
    int v[4], local = 0;
    #pragma unroll
    for (int k = 0; k < 4; k++) { v[k] = (base + k < n) ? deg[base + k] : 0; local += v[k]; }
    ts[t] = local; __syncthreads();
    for (int off = 1; off < 256; off <<= 1) {
        int val = (t >= off) ? ts[t - off] : 0;
        __syncthreads();
        ts[t] += val;
        __syncthreads();
    }
    int run = ts[t] - local;
    #pragma unroll
    for (int k = 0; k < 4; k++) { if (base + k < n) rowptr[base + k] = run; run += v[k]; }
    if (t == 255) bsum[blockIdx.x] = ts[255];
}

__global__ __launch_bounds__(256) void k_scan2(
    int* __restrict__ bsum, int* __restrict__ rowptr, int nb, int n)
{
    __shared__ int ts[256];
    int t = threadIdx.x;
    int base = t * 4;
    int v[4], local = 0;
    #pragma unroll
    for (int k = 0; k < 4; k++) { v[k] = (base + k < nb) ? bsum[base + k] : 0; local += v[k]; }
    ts[t] = local; __syncthreads();
    for (int off = 1; off < 256; off <<= 1) {
        int val = (t >= off) ? ts[t - off] : 0;
        __syncthreads();
        ts[t] += val;
        __syncthreads();
    }
    int run = ts[t] - local;
    #pragma unroll
    for (int k = 0; k < 4; k++) { if (base + k < nb) bsum[base + k] = run; run += v[k]; }
    if (t == 255) rowptr[n] = ts[255];       // grand total
}

__global__ __launch_bounds__(256) void k_scan3(
    int* __restrict__ rowptr, int* __restrict__ cursor,
    const int* __restrict__ bsum, int n)
{
    int add = bsum[blockIdx.x];
    int base = blockIdx.x * 1024 + threadIdx.x * 4;
    #pragma unroll
    for (int k = 0; k < 4; k++) {
        int i = base + k;
        if (i < n) { int r = rowptr[i] + add; rowptr[i] = r; cursor[i] = r; }
    }
}

// ---------------------------------------------------------------------------
// XCD-owned permute: same group structure as k_hist. Group g commits only
// edges with dst in its range -> every nbr/cursor line is written by exactly
// one XCD -> lines accumulate ~16 entries before one writeback (round-6's
// 51.5 MB WRITE_SIZE was cross-XCD partial-line ping-pong).
// ---------------------------------------------------------------------------
__global__ __launch_bounds__(256) void k_permute(
    const int* __restrict__ srcs, const int* __restrict__ dsts,
    int* __restrict__ cursor, int* __restrict__ nbr, int n_edges, int n_nodes)
{
    const int grp = blockIdx.x & (NXCD - 1);
    const int gidx = blockIdx.x >> 3;
    const int gstride = (gridDim.x >> 3) * 256;
    const int range = (n_nodes + NXCD - 1) / NXCD;
    const int lo = grp * range;
    const int hi = min(n_nodes, lo + range);
    for (int e = gidx * 256 + threadIdx.x; e < n_edges; e += gstride) {
        int d = dsts[e];
        if (d >= lo && d < hi) {
            int s = srcs[e];
            if ((unsigned)s < (unsigned)n_nodes) {
                int pos = atomicAdd(&cursor[d], 1);
                nbr[pos] = s;
            }
        }
    }
}

// ---------------------------------------------------------------------------
// Fused SAGE layer: one block per 16-node tile.
//  Phase 1 (gather): wave w handles nodes base+w*4..+3; per node, lane =
//    (neighbor slot g8 0..7) x (channel chunk l8 0..7, 16B); LDS round-trip
//    reduce across slots (wave-private, no barrier); bf16 mean row -> shared
//    A-tile (stride TROW=72).
//  Phase 2 (MFMA): after one __syncthreads, wave w computes output-channel
//    slice [w*16, w*16+16): 4x mfma_f32_16x16x32_bf16 with per-wave weight
//    slice (4 short8 frags), bias in acc init.
//  Epilogue: ReLU -> h row (HEAD=false) or cross-wave reduce + sigmoid -> out.
// C/D layout: col = lane&15, row = (lane>>4)*4 + reg (verified rounds 4-6).
// XMODE 0: xin dtype per flag (x). XMODE 1: xin is bf16 (h).
// ---------------------------------------------------------------------------
template <int XMODE, bool HEAD>
__global__ __launch_bounds__(256) void k_layer(
    const int* __restrict__ flag, const void* __restrict__ xin,
    const int* __restrict__ nbr, const int* __restrict__ rowptr,
    const void* __restrict__ w_l, const void* __restrict__ bias,
    const void* __restrict__ w_r,
    const void* __restrict__ w_out, const void* __restrict__ b_out,
    void* __restrict__ outp, int n_nodes)
{
    __shared__ float red[4][8 * CH];            // 8 KB reduce scratch
    __shared__ unsigned short tile[TILE * TROW];// 2.25 KB A-tile (mean rows)
    __shared__ float hred[4][TILE];             // head partials
    const int isbf = flag[0];
    const bool xbf = (XMODE == 1) ? true : (isbf != 0);
    const int lane = threadIdx.x & 63;
    const int wid  = threadIdx.x >> 6;
    const int l8 = lane & 7, g8 = lane >> 3;
    const int n_ = lane & 15, q_ = lane >> 4;

    // per-wave weight slice: out channels [wid*16, wid*16+16)
    short8 wlf[2], wrf[2];
    float bv, wov = 0.0f;
    {
        int row = wid * 16 + n_;
        if (isbf) {
            const unsigned short* wl = (const unsigned short*)w_l;
            const unsigned short* wr = (const unsigned short*)w_r;
            wlf[0] = *(const short8*)(wl + row * CH + q_ * 8);
            wlf[1] = *(const short8*)(wl + row * CH + 32 + q_ * 8);
            wrf[0] = *(const short8*)(wr + row * CH + q_ * 8);
            wrf[1] = *(const short8*)(wr + row * CH + 32 + q_ * 8);
            bv = bf2f(((const unsigned short*)bias)[row]);
            if (HEAD) wov = bf2f(((const unsigned short*)w_out)[row]);
        } else {
            const float* wl = (const float*)w_l;
            const float* wr = (const float*)w_r;
            #pragma unroll
            for (int j = 0; j < 8; j++) {
                wlf[0][j] = (short)f2bf(wl[row * CH + q_ * 8 + j]);
                wlf[1][j] = (short)f2bf(wl[row * CH + 32 + q_ * 8 + j]);
                wrf[0][j] = (short)f2bf(wr[row * CH + q_ * 8 + j]);
                wrf[1][j] = (short)f2bf(wr[row * CH + 32 + q_ * 8 + j]);
            }
            bv = ((const float*)bias)[row];
            if (HEAD) wov = ((const float*)w_out)[row];
        }
    }

    const unsigned short* xu = (const unsigned short*)xin;
    const float*          xf = (const float*)xin;
    const int base = blockIdx.x * TILE;
    float* rb = red[wid];

    // ---- phase 1: gather-mean, 4 nodes per wave ----
    for (int j = 0; j < 4; j++) {
        int node = base + wid * 4 + j;
        int row = 0, d = 0;
        if (node < n_nodes) { row = rowptr[node]; d = rowptr[node + 1] - row; }
        floatx4 a0 = {0, 0, 0, 0}, a1 = {0, 0, 0, 0};
        for (int it = 0; it < d; it += 16) {
            int i0 = it + g8;
            int i1 = it + 8 + g8;
            int s0 = (i0 < d) ? nbr[row + i0] : -1;
            int s1 = (i1 < d) ? nbr[row + i1] : -1;
            if (s0 >= 0) {
                if (xbf) {
                    short8 v = *(const short8*)(xu + (size_t)s0 * CH + l8 * 8);
                    #pragma unroll
                    for (int k = 0; k < 4; k++) a0[k] += bf2f((unsigned short)v[k]);
                    #pragma unroll
                    for (int k = 0; k < 4; k++) a1[k] += bf2f((unsigned short)v[4 + k]);
                } else {
                    const float* p = xf + (size_t)s0 * CH + l8 * 8;
                    a0 += *(const floatx4*)p; a1 += *(const floatx4*)(p + 4);
                }
            }
            if (s1 >= 0) {
                if (xbf) {
                    short8 v = *(const short8*)(xu + (size_t)s1 * CH + l8 * 8);
                    #pragma unroll
                    for (int k = 0; k < 4; k++) a0[k] += bf2f((unsigned short)v[k]);
                    #pragma unroll
                    for (int k = 0; k < 4; k++) a1[k] += bf2f((unsigned short)v[4 + k]);
                } else {
                    const float* p = xf + (size_t)s1 * CH + l8 * 8;
                    a0 += *(const floatx4*)p; a1 += *(const floatx4*)(p + 4);
                }
            }
        }
        // wave-private LDS reduce across the 8 neighbor slots
        *(floatx4*)&rb[g8 * CH + l8 * 8]     = a0;
        *(floatx4*)&rb[g8 * CH + l8 * 8 + 4] = a1;
        float s = 0.0f;
        #pragma unroll
        for (int g = 0; g < 8; g++) s += rb[g * CH + lane];
        float inv = 1.0f / (float)max(d, 1);
        tile[(wid * 4 + j) * TROW + lane] = f2bf(s * inv);
    }
    __syncthreads();

    // ---- phase 2: MFMA on the 16-node tile, per-wave 16-col slice ----
    short8 am0 = *(const short8*)(tile + n_ * TROW + q_ * 8);
    short8 am1 = *(const short8*)(tile + n_ * TROW + 32 + q_ * 8);
    int node_m = base + n_;
    int node_c = (node_m < n_nodes) ? node_m : 0;
    short8 ax0, ax1;
    if (xbf) {
        ax0 = *(const short8*)(xu + (size_t)node_c * CH + q_ * 8);
        ax1 = *(const short8*)(xu + (size_t)node_c * CH + 32 + q_ * 8);
    } else {
        const float* p = xf + (size_t)node_c * CH;
        #pragma unroll
        for (int j = 0; j < 8; j++) {
            ax0[j] = (short)f2bf(p[q_ * 8 + j]);
            ax1[j] = (short)f2bf(p[32 + q_ * 8 + j]);
        }
    }
    floatx4 acc = (floatx4){bv, bv, bv, bv};
    acc = __builtin_amdgcn_mfma_f32_16x16x32_bf16(am0, wlf[0], acc, 0, 0, 0);
    acc = __builtin_amdgcn_mfma_f32_16x16x32_bf16(am1, wlf[1], acc, 0, 0, 0);
    acc = __builtin_amdgcn_mfma_f32_16x16x32_bf16(ax0, wrf[0], acc, 0, 0, 0);
    acc = __builtin_amdgcn_mfma_f32_16x16x32_bf16(ax1, wrf[1], acc, 0, 0, 0);

    if (!HEAD) {
        unsigned short* ho = (unsigned short*)outp;
        int c = wid * 16 + n_;
        #pragma unroll
        for (int reg = 0; reg < 4; reg++) {
            int node_r = base + q_ * 4 + reg;
            if (node_r < n_nodes)
                ho[(size_t)node_r * CH + c] = f2bf(fmaxf(acc[reg], 0.0f));
        }
    } else {
        float p[4];
        #pragma unroll
        for (int reg = 0; reg < 4; reg++) p[reg] = fmaxf(acc[reg], 0.0f) * wov;
        #pragma unroll
        for (int off = 1; off < 16; off <<= 1) {
            #pragma unroll
            for (int reg = 0; reg < 4; reg++) p[reg] += __shfl_xor(p[reg], off);
        }
        if (n_ == 0) {
            #pragma unroll
            for (int reg = 0; reg < 4; reg++) hred[wid][q_ * 4 + reg] = p[reg];
        }
        __syncthreads();
        if (threadIdx.x < TILE) {
            int node_r = base + threadIdx.x;
            if (node_r < n_nodes) {
                float v = hred[0][threadIdx.x] + hred[1][threadIdx.x]
                        + hred[2][threadIdx.x] + hred[3][threadIdx.x];
                float bo = isbf ? bf2f(((const unsigned short*)b_out)[0])
                                : ((const float*)b_out)[0];
                float sg = 1.0f / (1.0f + expf(-(v + bo)));
                if (isbf) ((unsigned short*)outp)[node_r] = f2bf(sg);
                else      ((float*)outp)[node_r] = sg;
            }
        }
    }
}

extern "C" void kernel_launch(void* const* d_in, const int* in_sizes, int n_in,
                              void* d_out, int out_size, void* d_ws, size_t ws_size,
                              hipStream_t stream)
{
    const void* x    = d_in[0];
    const int*  ei   = (const int*)d_in[1];
    const void* w1_l = d_in[2];
    const void* b1   = d_in[3];
    const void* w1_r = d_in[4];
    const void* w2_l = d_in[5];
    const void* b2   = d_in[6];
    const void* w2_r = d_in[7];
    const void* wout = d_in[8];
    const void* bout = d_in[9];

    int n_nodes = out_size;
    int n_edges = in_sizes[1] / 2;
    const int* srcs = ei;
    const int* dsts = ei + n_edges;

    // ws: [flag][deg n][rowptr n+1][cursor n][bsum 1024][nbr E][h n*64 bf16]
    char* wsb = (char*)d_ws;
    size_t off = 0;
    auto carve = [&](size_t bytes) { size_t p = off; off = (off + bytes + 255) & ~(size_t)255; return p; };
    size_t flag_off = carve(sizeof(int));
    size_t deg_off  = carve((size_t)n_nodes * sizeof(int));
    size_t row_off  = carve((size_t)(n_nodes + 1) * sizeof(int));
    size_t cur_off  = carve((size_t)n_nodes * sizeof(int));
    size_t bs_off   = carve(1024 * sizeof(int));
    size_t nbr_off  = carve((size_t)n_edges * sizeof(int));
    size_t h_off    = carve((size_t)n_nodes * CH * sizeof(unsigned short));
    int* flag   = (int*)(wsb + flag_off);
    int* deg    = (int*)(wsb + deg_off);
    int* rowptr = (int*)(wsb + row_off);
    int* cursor = (int*)(wsb + cur_off);
    int* bsum   = (int*)(wsb + bs_off);
    int* nbr    = (int*)(wsb + nbr_off);
    unsigned short* h = (unsigned short*)(wsb + h_off);

    int xblocks = 2048;                        // XCD-owned hist/permute: 256 blocks/group
    int nb1     = (n_nodes + 1023) / 1024;
    int lblocks = (n_nodes + TILE - 1) / TILE; // fused layer: 1 block per 16-node tile

    hipMemsetAsync(deg, 0, (size_t)n_nodes * sizeof(int), stream);

    // CSR build (+ dtype detect inside k_hist)
    k_hist<<<xblocks, 256, 0, stream>>>((const unsigned short*)x, srcs, dsts, deg, flag, n_edges, n_nodes);
    k_scan1<<<nb1, 256, 0, stream>>>(deg, rowptr, bsum, n_nodes);
    k_scan2<<<1, 256, 0, stream>>>(bsum, rowptr, nb1, n_nodes);
    k_scan3<<<nb1, 256, 0, stream>>>(rowptr, cursor, bsum, n_nodes);
    k_permute<<<xblocks, 256, 0, stream>>>(srcs, dsts, cursor, nbr, n_edges, n_nodes);

    // layer 1: x -> h ; layer 2 + head: h -> out
    k_layer<0, false><<<lblocks, 256, 0, stream>>>(flag, x, nbr, rowptr,
        w1_l, b1, w1_r, nullptr, nullptr, h, n_nodes);
    k_layer<1, true><<<lblocks, 256, 0, stream>>>(flag, h, nbr, rowptr,
        w2_l, b2, w2_r, wout, bout, d_out, n_nodes);
}

// Round 8
// 282.993 us; speedup vs baseline: 1.0522x; 1.0522x over previous
//
#include <hip/hip_runtime.h>
#include <hip/hip_bf16.h>
#include <math.h>

#define CH 64
#define TILE 16
#define NXCD 8

typedef short short8 __attribute__((ext_vector_type(8)));
typedef float floatx4 __attribute__((ext_vector_type(4)));

__device__ __forceinline__ float bf2f(unsigned short u) {
    return __uint_as_float(((unsigned int)u) << 16);
}
__device__ __forceinline__ unsigned short f2bf(float f) {
    unsigned int x = __float_as_uint(f);
    unsigned int r = (x + 0x7fff + ((x >> 16) & 1)) >> 16;   // RNE
    return (unsigned short)r;
}

// ---------------------------------------------------------------------------
// Single-pass degree histogram (validity check matches k_permute exactly so
// deg == committed entries). Block 0 runs the bf16-vs-fp32 dtype detector.
// ---------------------------------------------------------------------------
__global__ __launch_bounds__(256) void k_hist(
    const unsigned short* __restrict__ x,
    const int* __restrict__ srcs, const int* __restrict__ dsts,
    int* __restrict__ deg, int* __restrict__ flag,
    int n_edges, int n_nodes)
{
    if (blockIdx.x == 0 && threadIdx.x < 64) {
        unsigned short u = x[2 * threadIdx.x];
        int ex = (u >> 7) & 0xFF;
        bool insane = (ex < 0x60) || (ex > 0x9F);
        unsigned long long m = __ballot(insane);
        if (threadIdx.x == 0) flag[0] = (__popcll(m) > 16) ? 0 : 1;
    }
    int e = blockIdx.x * 256 + threadIdx.x;
    if (e >= n_edges) return;
    int d = dsts[e], s = srcs[e];
    if ((unsigned)d < (unsigned)n_nodes && (unsigned)s < (unsigned)n_nodes)
        atomicAdd(&deg[d], 1);
}

// ---------------------------------------------------------------------------
// Exclusive scan: per-1024 block partials -> block-sum scan -> add-back.
// rowptr has n+1 entries; k_scan2 writes rowptr[n] = total.
// ---------------------------------------------------------------------------
__global__ __launch_bounds__(256) void k_scan1(
    const int* __restrict__ deg, int* __restrict__ rowptr,
    int* __restrict__ bsum, int n)
{
    __shared__ int ts[256];
    int t = threadIdx.x;
    int base = blockIdx.x * 1024 + t * 4;
    int v[4], local = 0;
    #pragma unroll
    for (int k = 0; k < 4; k++) { v[k] = (base + k < n) ? deg[base + k] : 0; local += v[k]; }
    ts[t] = local; __syncthreads();
    for (int off = 1; off < 256; off <<= 1) {
        int val = (t >= off) ? ts[t - off] : 0;
        __syncthreads();
        ts[t] += val;
        __syncthreads();
    }
    int run = ts[t] - local;
    #pragma unroll
    for (int k = 0; k < 4; k++) { if (base + k < n) rowptr[base + k] = run; run += v[k]; }
    if (t == 255) bsum[blockIdx.x] = ts[255];
}

__global__ __launch_bounds__(256) void k_scan2(
    int* __restrict__ bsum, int* __restrict__ rowptr, int nb, int n)
{
    __shared__ int ts[256];
    int t = threadIdx.x;
    int base = t * 4;
    int v[4], local = 0;
    #pragma unroll
    for (int k = 0; k < 4; k++) { v[k] = (base + k < nb) ? bsum[base + k] : 0; local += v[k]; }
    ts[t] = local; __syncthreads();
    for (int off = 1; off < 256; off <<= 1) {
        int val = (t >= off) ? ts[t - off] : 0;
        __syncthreads();
        ts[t] += val;
        __syncthreads();
    }
    int run = ts[t] - local;
    #pragma unroll
    for (int k = 0; k < 4; k++) { if (base + k < nb) bsum[base + k] = run; run += v[k]; }
    if (t == 255) rowptr[n] = ts[255];       // grand total
}

__global__ __launch_bounds__(256) void k_scan3(
    int* __restrict__ rowptr, int* __restrict__ cursor,
    const int* __restrict__ bsum, int n)
{
    int add = bsum[blockIdx.x];
    int base = blockIdx.x * 1024 + threadIdx.x * 4;
    #pragma unroll
    for (int k = 0; k < 4; k++) {
        int i = base + k;
        if (i < n) { int r = rowptr[i] + add; rowptr[i] = r; cursor[i] = r; }
    }
}

// ---------------------------------------------------------------------------
// XCD-owned permute: blocks with (blockIdx&7)==g scan all edges, commit only
// dsts in range g -> every nbr/cursor line is written by exactly one XCD
// (kills cross-XCD partial-line writeback ping-pong; verified round 7).
// blockIdx&7 ~ XCD id is a perf heuristic only; atomics are device-scope.
// ---------------------------------------------------------------------------
__global__ __launch_bounds__(256) void k_permute(
    const int* __restrict__ srcs, const int* __restrict__ dsts,
    int* __restrict__ cursor, int* __restrict__ nbr, int n_edges, int n_nodes)
{
    const int grp = blockIdx.x & (NXCD - 1);
    const int gidx = blockIdx.x >> 3;
    const int gstride = (gridDim.x >> 3) * 256;
    const int range = (n_nodes + NXCD - 1) / NXCD;
    const int lo = grp * range;
    const int hi = min(n_nodes, lo + range);
    for (int e = gidx * 256 + threadIdx.x; e < n_edges; e += gstride) {
        int d = dsts[e];
        if (d >= lo && d < hi) {
            int s = srcs[e];
            if ((unsigned)s < (unsigned)n_nodes) {
                int pos = atomicAdd(&cursor[d], 1);
                nbr[pos] = s;
            }
        }
    }
}

// ---------------------------------------------------------------------------
// Gather-mean v2: 4 nodes per wave, built for memory-level parallelism.
// lane = t(node 0..3 | lane>>4) x s(parity | (lane>>3)&1) x c(16B chunk |
// lane&7). Per 16-neighbor block: 8 independent nbr-index loads + 8
// independent 16B row loads per lane, no LDS; slot reduce = one shfl_xor(8);
// mean row stored bf16 straight from registers (8 lanes x 16B = 128 B/node).
// XMODE 0: xin dtype per flag. XMODE 1: xin is bf16.
// ---------------------------------------------------------------------------
template <int XMODE>
__global__ __launch_bounds__(256) void k_gather(
    const int* __restrict__ flag, const void* __restrict__ xin,
    const int* __restrict__ nbr, const int* __restrict__ rowptr,
    unsigned short* __restrict__ meanout, int n_nodes)
{
    const bool xbf = (XMODE == 1) ? true : (flag[0] != 0);
    const int lane = threadIdx.x & 63;
    const int wid  = threadIdx.x >> 6;
    const int t = lane >> 4;          // node slot
    const int s = (lane >> 3) & 1;    // neighbor parity
    const int c = lane & 7;           // 16B channel chunk

    int wbase = (blockIdx.x * 4 + wid) * 4;
    if (wbase >= n_nodes) return;
    int node = wbase + t;
    bool nv = node < n_nodes;
    int r0 = 0, d = 0;
    if (nv) { r0 = rowptr[node]; d = rowptr[node + 1] - r0; }

    // wave-uniform loop bound (within a node all 16 lanes share d)
    int dmax = d;
    dmax = max(dmax, __shfl_xor(dmax, 16));
    dmax = max(dmax, __shfl_xor(dmax, 32));

    const unsigned short* xu = (const unsigned short*)xin;
    const float*          xf = (const float*)xin;

    if (xbf) {
        floatx4 a0 = {0, 0, 0, 0}, a1 = {0, 0, 0, 0};
        for (int jb = 0; jb < dmax; jb += 16) {
            #pragma unroll
            for (int k = 0; k < 8; k++) {
                int j = jb + k * 2 + s;
                if (j < d) {
                    int src = nbr[r0 + j];
                    short8 v = *(const short8*)(xu + (size_t)src * CH + c * 8);
                    #pragma unroll
                    for (int i = 0; i < 4; i++) a0[i] += bf2f((unsigned short)v[i]);
                    #pragma unroll
                    for (int i = 0; i < 4; i++) a1[i] += bf2f((unsigned short)v[4 + i]);
                }
            }
        }
        #pragma unroll
        for (int i = 0; i < 4; i++) {
            a0[i] += __shfl_xor(a0[i], 8);
            a1[i] += __shfl_xor(a1[i], 8);
        }
        if (nv && (lane & 8) == 0) {
            float inv = 1.0f / (float)max(d, 1);
            short8 mv;
            #pragma unroll
            for (int i = 0; i < 4; i++) {
                mv[i]     = (short)f2bf(a0[i] * inv);
                mv[4 + i] = (short)f2bf(a1[i] * inv);
            }
            *(short8*)(meanout + (size_t)node * CH + c * 8) = mv;
        }
    } else {
        // fp32 input (cold correctness path): 16 lanes/node, lane covers 4 ch
        int j16 = lane & 15;
        floatx4 acc = {0, 0, 0, 0};
        for (int j = 0; j < d; j++) {
            int src = nbr[r0 + j];
            acc += *(const floatx4*)(xf + (size_t)src * CH + j16 * 4);
        }
        if (nv) {
            float inv = 1.0f / (float)max(d, 1);
            unsigned short* mp = meanout + (size_t)node * CH + j16 * 4;
            #pragma unroll
            for (int i = 0; i < 4; i++) mp[i] = f2bf(acc[i] * inv);
        }
    }
}

// ---------------------------------------------------------------------------
// MFMA tile kernel (verified round 5): 16-node tile per wave, grid-stride.
//   D = mean@Wl^T + x_self@Wr^T + bias ; ReLU -> h, or fused head -> out.
// Weight B-frags preloaded to registers; A-frags streamed from mean/x.
// C/D layout: col = lane&15, row = (lane>>4)*4 + reg.
// ---------------------------------------------------------------------------
template <int XMODE, bool HEAD>
__global__ __launch_bounds__(256) void k_mm(
    const int* __restrict__ flag, const void* __restrict__ xin,
    const unsigned short* __restrict__ meanin,
    const void* __restrict__ w_l, const void* __restrict__ bias,
    const void* __restrict__ w_r,
    const void* __restrict__ w_out, const void* __restrict__ b_out,
    void* __restrict__ outp, int n_nodes)
{
    const int isbf = flag[0];
    const bool xbf = (XMODE == 1) ? true : (isbf != 0);
    const int lane = threadIdx.x & 63;
    const int wid  = threadIdx.x >> 6;
    const int n_ = lane & 15;
    const int q_ = lane >> 4;

    // preload weight B-frags: lane holds B[k=q_*8+j][n=n_], frag kc: k0=kc*32
    short8 wlf[4][2], wrf[4][2];
    float bv[4], wov[4];
    #pragma unroll
    for (int t = 0; t < 4; t++) {
        int row = t * 16 + n_;
        if (isbf) {
            const unsigned short* wl = (const unsigned short*)w_l;
            const unsigned short* wr = (const unsigned short*)w_r;
            #pragma unroll
            for (int kc = 0; kc < 2; kc++) {
                int k0 = kc * 32 + q_ * 8;
                wlf[t][kc] = *(const short8*)(wl + row * CH + k0);
                wrf[t][kc] = *(const short8*)(wr + row * CH + k0);
            }
            bv[t] = bf2f(((const unsigned short*)bias)[row]);
            if (HEAD) wov[t] = bf2f(((const unsigned short*)w_out)[row]);
        } else {
            const float* wl = (const float*)w_l;
            const float* wr = (const float*)w_r;
            #pragma unroll
            for (int kc = 0; kc < 2; kc++) {
                int k0 = kc * 32 + q_ * 8;
                #pragma unroll
                for (int j = 0; j < 8; j++) {
                    wlf[t][kc][j] = (short)f2bf(wl[row * CH + k0 + j]);
                    wrf[t][kc][j] = (short)f2bf(wr[row * CH + k0 + j]);
                }
            }
            bv[t] = ((const float*)bias)[row];
            if (HEAD) wov[t] = ((const float*)w_out)[row];
        }
    }

    const unsigned short* xu = (const unsigned short*)xin;
    const float*          xf = (const float*)xin;
    int n_tiles = (n_nodes + TILE - 1) / TILE;
    int gw = blockIdx.x * 4 + wid;
    int nw = gridDim.x * 4;

    for (int tb = gw; tb < n_tiles; tb += nw) {
        int base = tb * TILE;
        int node_m = base + n_;
        int node_c = (node_m < n_nodes) ? node_m : 0;
        short8 am0 = *(const short8*)(meanin + (size_t)node_c * CH + q_ * 8);
        short8 am1 = *(const short8*)(meanin + (size_t)node_c * CH + 32 + q_ * 8);
        short8 ax0, ax1;
        if (xbf) {
            ax0 = *(const short8*)(xu + (size_t)node_c * CH + q_ * 8);
            ax1 = *(const short8*)(xu + (size_t)node_c * CH + 32 + q_ * 8);
        } else {
            const float* p = xf + (size_t)node_c * CH;
            #pragma unroll
            for (int j = 0; j < 8; j++) {
                ax0[j] = (short)f2bf(p[q_ * 8 + j]);
                ax1[j] = (short)f2bf(p[32 + q_ * 8 + j]);
            }
        }
        floatx4 acc[4];
        #pragma unroll
        for (int t = 0; t < 4; t++) {
            acc[t] = (floatx4){bv[t], bv[t], bv[t], bv[t]};
            acc[t] = __builtin_amdgcn_mfma_f32_16x16x32_bf16(am0, wlf[t][0], acc[t], 0, 0, 0);
            acc[t] = __builtin_amdgcn_mfma_f32_16x16x32_bf16(am1, wlf[t][1], acc[t], 0, 0, 0);
            acc[t] = __builtin_amdgcn_mfma_f32_16x16x32_bf16(ax0, wrf[t][0], acc[t], 0, 0, 0);
            acc[t] = __builtin_amdgcn_mfma_f32_16x16x32_bf16(ax1, wrf[t][1], acc[t], 0, 0, 0);
        }
        if (!HEAD) {
            unsigned short* ho = (unsigned short*)outp;
            #pragma unroll
            for (int t = 0; t < 4; t++) {
                int cc = t * 16 + n_;
                #pragma unroll
                for (int reg = 0; reg < 4; reg++) {
                    int node_r = base + q_ * 4 + reg;
                    if (node_r < n_nodes)
                        ho[(size_t)node_r * CH + cc] = f2bf(fmaxf(acc[t][reg], 0.0f));
                }
            }
        } else {
            float p[4] = {0, 0, 0, 0};
            #pragma unroll
            for (int t = 0; t < 4; t++) {
                #pragma unroll
                for (int reg = 0; reg < 4; reg++)
                    p[reg] += fmaxf(acc[t][reg], 0.0f) * wov[t];
            }
            #pragma unroll
            for (int off = 1; off < 16; off <<= 1) {
                #pragma unroll
                for (int reg = 0; reg < 4; reg++)
                    p[reg] += __shfl_xor(p[reg], off);
            }
            if (n_ == 0) {
                float bo = isbf ? bf2f(((const unsigned short*)b_out)[0])
                                : ((const float*)b_out)[0];
                #pragma unroll
                for (int reg = 0; reg < 4; reg++) {
                    int node_r = base + q_ * 4 + reg;
                    if (node_r < n_nodes) {
                        float sg = 1.0f / (1.0f + expf(-(p[reg] + bo)));
                        if (isbf) ((unsigned short*)outp)[node_r] = f2bf(sg);
                        else      ((float*)outp)[node_r] = sg;
                    }
                }
            }
        }
    }
}

extern "C" void kernel_launch(void* const* d_in, const int* in_sizes, int n_in,
                              void* d_out, int out_size, void* d_ws, size_t ws_size,
                              hipStream_t stream)
{
    const void* x    = d_in[0];
    const int*  ei   = (const int*)d_in[1];
    const void* w1_l = d_in[2];
    const void* b1   = d_in[3];
    const void* w1_r = d_in[4];
    const void* w2_l = d_in[5];
    const void* b2   = d_in[6];
    const void* w2_r = d_in[7];
    const void* wout = d_in[8];
    const void* bout = d_in[9];

    int n_nodes = out_size;
    int n_edges = in_sizes[1] / 2;
    const int* srcs = ei;
    const int* dsts = ei + n_edges;

    // ws: [flag][deg n][rowptr n+1][cursor n][bsum 1024][nbr E][mean n*64][h n*64]
    char* wsb = (char*)d_ws;
    size_t off = 0;
    auto carve = [&](size_t bytes) { size_t p = off; off = (off + bytes + 255) & ~(size_t)255; return p; };
    size_t flag_off = carve(sizeof(int));
    size_t deg_off  = carve((size_t)n_nodes * sizeof(int));
    size_t row_off  = carve((size_t)(n_nodes + 1) * sizeof(int));
    size_t cur_off  = carve((size_t)n_nodes * sizeof(int));
    size_t bs_off   = carve(1024 * sizeof(int));
    size_t nbr_off  = carve((size_t)n_edges * sizeof(int));
    size_t mean_off = carve((size_t)n_nodes * CH * sizeof(unsigned short));
    size_t h_off    = carve((size_t)n_nodes * CH * sizeof(unsigned short));
    int* flag   = (int*)(wsb + flag_off);
    int* deg    = (int*)(wsb + deg_off);
    int* rowptr = (int*)(wsb + row_off);
    int* cursor = (int*)(wsb + cur_off);
    int* bsum   = (int*)(wsb + bs_off);
    int* nbr    = (int*)(wsb + nbr_off);
    unsigned short* mean = (unsigned short*)(wsb + mean_off);
    unsigned short* h    = (unsigned short*)(wsb + h_off);

    int eblocks = (n_edges + 255) / 256;
    int xblocks = 2048;                          // XCD-owned permute
    int nb1     = (n_nodes + 1023) / 1024;
    int gblocks = (n_nodes + 15) / 16;           // gather: 4 nodes/wave, 4 waves
    int mblocks = 512;                           // mm: grid-stride over tiles

    hipMemsetAsync(deg, 0, (size_t)n_nodes * sizeof(int), stream);

    // CSR build (+ dtype detect inside k_hist)
    k_hist<<<eblocks, 256, 0, stream>>>((const unsigned short*)x, srcs, dsts, deg, flag, n_edges, n_nodes);
    k_scan1<<<nb1, 256, 0, stream>>>(deg, rowptr, bsum, n_nodes);
    k_scan2<<<1, 256, 0, stream>>>(bsum, rowptr, nb1, n_nodes);
    k_scan3<<<nb1, 256, 0, stream>>>(rowptr, cursor, bsum, n_nodes);
    k_permute<<<xblocks, 256, 0, stream>>>(srcs, dsts, cursor, nbr, n_edges, n_nodes);

    // layer 1: x -> h
    k_gather<0><<<gblocks, 256, 0, stream>>>(flag, x, nbr, rowptr, mean, n_nodes);
    k_mm<0, false><<<mblocks, 256, 0, stream>>>(flag, x, mean, w1_l, b1, w1_r,
                                                nullptr, nullptr, h, n_nodes);
    // layer 2 + head: h -> out
    k_gather<1><<<gblocks, 256, 0, stream>>>(flag, h, nbr, rowptr, mean, n_nodes);
    k_mm<1, true><<<mblocks, 256, 0, stream>>>(flag, h, mean, w2_l, b2, w2_r,
                                               wout, bout, d_out, n_nodes);
}